// Round 6
// baseline (250.851 us; speedup 1.0000x reference)
//
#include <hip/hip_runtime.h>

#define BSZ 32
#define DIM 64
#define SEQ 2048
#define KE  1024
#define KC  128   // k-chunk staged in LDS
#define ST  128   // s-tile per block

// output offsets in floats
#define O0 0ull            // quantized_st [BS][D][S]
#define O1 4194304ull      // loss (scalar)
#define O2 4194305ull      // one_hot [BS][K][S]
#define O3 71303169ull     // indices [BS][S] (as float)
#define O4 71368705ull     // distance [BS][K][S]
#define O5 138477569ull    // unquantized [BS*S][D]
#define O6 142671873ull    // embeddings.T [K][D]

// lgkm-only barrier: does NOT drain vmcnt -> global stores stay in flight.
__device__ __forceinline__ void lds_barrier() {
    asm volatile("s_waitcnt lgkmcnt(0)" ::: "memory");
    __builtin_amdgcn_s_barrier();
}

// 16B-chunk swizzle within a 128-float row: bijection on chunk index 0..31.
// Read pattern [d][tx*8] (2 b128/thread) lands on 8 bank-quads 2-way (free).
__device__ __forceinline__ int swz(int j) {
    int t = j >> 1;
    return ((j & 1) << 6) + ((t & 7) << 2) + ((t >> 3) << 5);
}

// Kernel 0: transpose E -> out6 + aligned ws copy; b2[k] = ||e_k||^2; zero loss.
__global__ __launch_bounds__(256) void vq_prep(const float* __restrict__ E,
                                               float* __restrict__ out,
                                               float* __restrict__ et_ws,
                                               float* __restrict__ b2_ws) {
    __shared__ float T[64][65];
    const int tid  = threadIdx.x;
    const int lane = tid & 63;
    const int sub  = tid >> 6;
    const int k0   = blockIdx.x * 64;
    for (int dd = 0; dd < 16; ++dd) {
        int d = dd * 4 + sub;
        T[d][lane] = E[(size_t)d * KE + k0 + lane];
    }
    __syncthreads();
    for (int ii = 0; ii < 16; ++ii) {
        int kl = ii * 4 + sub;
        float v = T[lane][kl];
        out[O6 + (size_t)(k0 + kl) * 64 + lane] = v;
        et_ws[(size_t)(k0 + kl) * 64 + lane]    = v;
    }
    if (tid < 64) {
        float s = 0.f;
        #pragma unroll
        for (int d = 0; d < 64; ++d) {
            float v = T[d][tid];
            s = fmaf(v, v, s);
        }
        b2_ws[k0 + tid] = s;
    }
    if (blockIdx.x == 0 && tid == 0) out[O1] = 0.f;
}

// Kernel 1: register-tiled distance GEMM; swizzled LDS feed; e-prefetch to regs;
// lgkm-only barriers so dist/one_hot stores drain under compute; LDS-staged
// lane-consecutive flush; argmin; epilogues.
// grid = 32 b * 16 s-tiles; block 256 = (16 tx)*(16 ky); thread tile 8s x 8k.
__global__ __launch_bounds__(256, 2) void vq_main(const float* __restrict__ x,
                                                  const float* __restrict__ E,
                                                  const float* __restrict__ et,
                                                  const float* __restrict__ b2,
                                                  float* __restrict__ out) {
    __shared__ __align__(16) float xt[64 * ST];   // 32 KB, x-tile, swizzled rows
    __shared__ __align__(16) union UU {
        float e[64 * KC];                          // 32 KB: e-chunk (swizzled) / flush stage (linear)
        struct { float D[16][ST]; int Kk[16][ST]; } red;
        float qt[64 * ST];
    } u;
    __shared__ __align__(16) float a2s[ST];

    const int tid = threadIdx.x;
    const int tx  = tid & 15;      // s-group: s = tx*8 .. +8
    const int ky  = tid >> 4;      // k-group: k = kc + ky*8 .. +8
    const int b   = blockIdx.x >> 4;
    const int s0  = (blockIdx.x & 15) << 7;

    // prefetch e-chunk 0 into regs (flies under the x-stage)
    float4 er[8];
    #pragma unroll
    for (int i = 0; i < 8; ++i) {
        int f = (i << 8) + tid;
        int d = f >> 5, j = f & 31;
        er[i] = *(const float4*)(E + (size_t)d * KE + (j << 2));
    }

    // stage x-tile [64 d][128 s] swizzled
    {
        const float* xb = x + ((size_t)b << 17) + s0;    // D*S = 2^17
        #pragma unroll
        for (int i = 0; i < 8; ++i) {
            int f = (i << 8) + tid;
            int d = f >> 5, j = f & 31;
            float4 v = *(const float4*)(xb + ((size_t)d << 11) + (j << 2));
            *(float4*)&xt[d * ST + swz(j)] = v;
        }
    }
    __syncthreads();
    if (tid < ST) {
        const int wi = swz(tid >> 2) + (tid & 3);
        float sacc = 0.f;
        #pragma unroll
        for (int d = 0; d < 64; ++d) {
            float v = xt[d * ST + wi];
            sacc = fmaf(v, v, sacc);
        }
        a2s[tid] = sacc;
    }

    float bD[8];
    int   bK[8];
    #pragma unroll
    for (int j = 0; j < 8; ++j) { bD[j] = 3.4e38f; bK[j] = 0; }

    float* outD = out + O4 + ((size_t)b << 21) + s0;   // K*S = 2^21
    float* outH = out + O2 + ((size_t)b << 21) + s0;

    const int xw1 = ((tx & 7) << 2) + ((tx >> 3) << 5);   // swz(2tx)
    const int ew1 = ((ky & 7) << 2) + ((ky >> 3) << 5);   // swz(2ky)

    #pragma unroll 1
    for (int c = 0; c < KE / KC; ++c) {
        const int kc = c << 7;
        lds_barrier();   // (A) u.e free: prior flush LDS-reads done (c=0: trivially)
        // write prefetched e-chunk regs -> LDS (swizzled)
        #pragma unroll
        for (int i = 0; i < 8; ++i) {
            int f = (i << 8) + tid;
            int d = f >> 5, j = f & 31;
            *(float4*)&u.e[d * KC + swz(j)] = er[i];
        }
        lds_barrier();   // (B) u.e ready
        // issue next chunk's loads; they fly under the d-loop
        if (c < KE / KC - 1) {
            #pragma unroll
            for (int i = 0; i < 8; ++i) {
                int f = (i << 8) + tid;
                int d = f >> 5, j = f & 31;
                er[i] = *(const float4*)(E + (size_t)d * KE + (kc + KC) + (j << 2));
            }
        }

        float acc[8][8];
        #pragma unroll
        for (int jk = 0; jk < 8; ++jk)
            #pragma unroll
            for (int js = 0; js < 8; ++js) acc[jk][js] = 0.f;

        #pragma unroll 2
        for (int d = 0; d < 64; ++d) {
            float4 xa  = *(const float4*)&xt[d * ST + xw1];
            float4 xb4 = *(const float4*)&xt[d * ST + xw1 + 64];
            float4 ea  = *(const float4*)&u.e[d * KC + ew1];
            float4 eb4 = *(const float4*)&u.e[d * KC + ew1 + 64];
            float xs[8] = {xa.x, xa.y, xa.z, xa.w, xb4.x, xb4.y, xb4.z, xb4.w};
            float es[8] = {ea.x, ea.y, ea.z, ea.w, eb4.x, eb4.y, eb4.z, eb4.w};
            #pragma unroll
            for (int jk = 0; jk < 8; ++jk)
                #pragma unroll
                for (int js = 0; js < 8; ++js)
                    acc[jk][js] = fmaf(es[jk], xs[js], acc[jk][js]);
        }

        // dist in-place + per-thread argmin (k ascending per thread)
        {
            float4 b2a = *(const float4*)(b2 + kc + ky * 8);
            float4 b2b = *(const float4*)(b2 + kc + ky * 8 + 4);
            float b2v[8] = {b2a.x, b2a.y, b2a.z, b2a.w, b2b.x, b2b.y, b2b.z, b2b.w};
            float4 av1 = *(const float4*)&a2s[tx * 8];
            float4 av2 = *(const float4*)&a2s[tx * 8 + 4];
            float a2v[8] = {av1.x, av1.y, av1.z, av1.w, av2.x, av2.y, av2.z, av2.w};
            #pragma unroll
            for (int jk = 0; jk < 8; ++jk) {
                const int k = kc + ky * 8 + jk;
                #pragma unroll
                for (int js = 0; js < 8; ++js) {
                    float dist = fmaf(-2.f, acc[jk][js], a2v[js] + b2v[jk]);
                    acc[jk][js] = dist;
                    if (dist < bD[js]) { bD[js] = dist; bK[js] = k; }
                }
            }
        }

        // flush dist + one_hot zeros via u.e (dead, reused LINEAR):
        // half h = k-rows [kc+64h, +64); stores fly (no vmcnt drain).
        #pragma unroll
        for (int h = 0; h < 2; ++h) {
            lds_barrier();   // h=0: d-loop e-reads done; h=1: prior flush reads done
            if ((ky >> 3) == h) {
                const int r0 = (ky & 7) << 3;
                #pragma unroll
                for (int jk = 0; jk < 8; ++jk) {
                    float4 lo = {acc[jk][0], acc[jk][1], acc[jk][2], acc[jk][3]};
                    float4 hi = {acc[jk][4], acc[jk][5], acc[jk][6], acc[jk][7]};
                    *(float4*)&u.e[(r0 + jk) * ST + tx * 8]     = lo;
                    *(float4*)&u.e[(r0 + jk) * ST + tx * 8 + 4] = hi;
                }
            }
            lds_barrier();
            const int kb = kc + (h << 6);
            #pragma unroll
            for (int i = 0; i < 32; ++i) {
                int f   = (i << 8) + tid;       // lane-consecutive
                int row = f >> 7;
                int sc  = f & 127;
                size_t off = ((size_t)(kb + row) << 11) + sc;
                float v = u.e[f];
                outD[off] = v;      // 64 consecutive lanes -> 4 lines/instr
                outH[off] = 0.f;
            }
        }
    }

    lds_barrier();   // last flush reads done before red overwrite
    #pragma unroll
    for (int js = 0; js < 8; ++js) {
        u.red.D[ky][tx * 8 + js]  = bD[js];
        u.red.Kk[ky][tx * 8 + js] = bK[js];
    }
    __syncthreads();   // FULL drain: all one_hot zeros visible before the 1.0 fix

    if (tid < ST) {
        float bDr = u.red.D[0][tid];
        int   bKr = u.red.Kk[0][tid];
        #pragma unroll
        for (int w = 1; w < 16; ++w) {
            float dw = u.red.D[w][tid];
            int   kw = u.red.Kk[w][tid];
            if (dw < bDr || (dw == bDr && kw < bKr)) { bDr = dw; bKr = kw; }  // global first-min
        }
        out[O3 + (size_t)b * SEQ + s0 + tid] = (float)bKr;
        out[O2 + ((size_t)b << 21) + ((size_t)bKr << 11) + s0 + tid] = 1.f;

        // gather codeword, fill qt column (linear), loss partial
        const float* q = et + ((size_t)bKr << 6);
        const int wi = swz(tid >> 2) + (tid & 3);
        float lsum = 0.f;
        #pragma unroll
        for (int i = 0; i < 16; ++i) {
            float4 q4 = ((const float4*)q)[i];
            float qs[4] = {q4.x, q4.y, q4.z, q4.w};
            #pragma unroll
            for (int j = 0; j < 4; ++j) {
                int d = i * 4 + j;
                u.qt[d * ST + tid] = qs[j];
                float df = qs[j] - xt[d * ST + wi];
                lsum = fmaf(df, df, lsum);
            }
        }
        #pragma unroll
        for (int m = 32; m >= 1; m >>= 1) lsum += __shfl_xor(lsum, m, 64);
        if ((tid & 63) == 0) atomicAdd(out + O1, lsum * (2.f / 4194304.f));
    }
    __syncthreads();

    // quantized_st out: [d][s] coalesced float4 (O0 aligned, qt linear)
    {
        float* oq = out + ((size_t)b << 17) + s0;
        #pragma unroll
        for (int i = 0; i < 8; ++i) {
            int f  = (i << 8) + tid;
            int d  = f >> 5;
            int sc = (f & 31) << 2;
            *(float4*)(oq + ((size_t)d << 11) + sc) = *(const float4*)&u.qt[d * ST + sc];
        }
    }
}

// Kernel 2: unquantized = x transposed to [BS*S][D]
__global__ __launch_bounds__(256) void vq_unq(const float* __restrict__ x,
                                              float* __restrict__ out) {
    __shared__ float T[64][65];
    const int tid  = threadIdx.x;
    const int lane = tid & 63;
    const int sub  = tid >> 6;
    const int b    = blockIdx.x >> 5;
    const int s0   = (blockIdx.x & 31) << 6;
    const float* xp = x + ((size_t)b << 17) + s0;
    for (int dd = 0; dd < 16; ++dd) {
        int d = dd * 4 + sub;
        T[d][lane] = xp[((size_t)d << 11) + lane];
    }
    __syncthreads();
    float* op = out + O5 + (((size_t)b << 11) + s0) * 64;
    for (int ii = 0; ii < 16; ++ii) {
        int sl = ii * 4 + sub;
        op[(size_t)sl * 64 + lane] = T[lane][sl];
    }
}

extern "C" void kernel_launch(void* const* d_in, const int* in_sizes, int n_in,
                              void* d_out, int out_size, void* d_ws, size_t ws_size,
                              hipStream_t stream) {
    const float* x = (const float*)d_in[0];
    const float* E = (const float*)d_in[1];
    float* out   = (float*)d_out;
    float* et_ws = (float*)d_ws;          // 65536 floats: E^T rows, 16B-aligned
    float* b2_ws = et_ws + 65536;         // 1024 floats
    vq_prep<<<16, 256, 0, stream>>>(E, out, et_ws, b2_ws);
    vq_main<<<512, 256, 0, stream>>>(x, E, et_ws, b2_ws, out);
    vq_unq<<<1024, 256, 0, stream>>>(x, out);
}

// Round 7
// 247.379 us; speedup vs baseline: 1.0140x; 1.0140x over previous
//
#include <hip/hip_runtime.h>

#define BSZ 32
#define DIM 64
#define SEQ 2048
#define KE  1024
#define KC  128   // k-chunk staged in LDS
#define ST  128   // s-tile per block

// output offsets in floats
#define O0 0ull            // quantized_st [BS][D][S]
#define O1 4194304ull      // loss (scalar)
#define O2 4194305ull      // one_hot [BS][K][S]
#define O3 71303169ull     // indices [BS][S] (as float)
#define O4 71368705ull     // distance [BS][K][S]
#define O5 138477569ull    // unquantized [BS*S][D]
#define O6 142671873ull    // embeddings.T [K][D]

// 16B store with only 4B alignment guarantee (O2/O4 are odd float offsets).
struct __attribute__((packed, aligned(4))) F4 { float x, y, z, w; };

// lgkm-only barrier: does NOT drain vmcnt -> global stores stay in flight
// across chunk boundaries and drain under the next chunk's compute.
__device__ __forceinline__ void lds_barrier() {
    asm volatile("s_waitcnt lgkmcnt(0)" ::: "memory");
    __builtin_amdgcn_s_barrier();
}

// Kernel 0: transpose E -> out6 + aligned ws copy; b2[k] = ||e_k||^2; zero loss.
__global__ __launch_bounds__(256) void vq_prep(const float* __restrict__ E,
                                               float* __restrict__ out,
                                               float* __restrict__ et_ws,
                                               float* __restrict__ b2_ws) {
    __shared__ float T[64][65];
    const int tid  = threadIdx.x;
    const int lane = tid & 63;
    const int sub  = tid >> 6;
    const int k0   = blockIdx.x * 64;
    for (int dd = 0; dd < 16; ++dd) {
        int d = dd * 4 + sub;
        T[d][lane] = E[(size_t)d * KE + k0 + lane];
    }
    __syncthreads();
    for (int ii = 0; ii < 16; ++ii) {
        int kl = ii * 4 + sub;
        float v = T[lane][kl];
        out[O6 + (size_t)(k0 + kl) * 64 + lane] = v;
        et_ws[(size_t)(k0 + kl) * 64 + lane]    = v;
    }
    if (tid < 64) {
        float s = 0.f;
        #pragma unroll
        for (int d = 0; d < 64; ++d) {
            float v = T[d][tid];
            s = fmaf(v, v, s);
        }
        b2_ws[k0 + tid] = s;
    }
    if (blockIdx.x == 0 && tid == 0) out[O1] = 0.f;
}

// Kernel 1: register-tiled distance GEMM, per-thread s-QUAD ownership so dist
// and one_hot stores are direct 16B full-line stores (no LDS flush stage);
// lgkm-only barriers keep stores in flight; argmin; all epilogues incl. unq.
// grid = 32 b * 16 s-tiles (512 = 2 blocks/CU exactly); block 256 = 16 tx * 16 ky.
// Thread tile: s in {tx*4..+3} u {64+tx*4..+3}, k in {kc+ky*8..+7}.
__global__ __launch_bounds__(256, 2) void vq_main(const float* __restrict__ x,
                                                  const float* __restrict__ E,
                                                  const float* __restrict__ et,
                                                  const float* __restrict__ b2,
                                                  float* __restrict__ out) {
    __shared__ __align__(16) float xt[64 * ST];   // 32 KB x-tile [d][s] linear
    __shared__ __align__(16) union UU {
        float e[64 * KC];                          // 32 KB e-chunk [d][k] linear
        struct { float D[16][ST]; int Kk[16][ST]; } red;
        float qt[64 * ST];
    } u;
    __shared__ __align__(16) float a2s[ST];

    const int tid = threadIdx.x;
    const int tx  = tid & 15;
    const int ky  = tid >> 4;
    const int b   = blockIdx.x >> 4;
    const int s0  = (blockIdx.x & 15) << 7;
    const int sq  = tx << 2;

    // prefetch e-chunk 0 into regs (flies under the x-stage)
    float4 er[8];
    #pragma unroll
    for (int i = 0; i < 8; ++i) {
        int f = (i << 8) + tid, d = f >> 5, j = f & 31;
        er[i] = *(const float4*)(E + (size_t)d * KE + (j << 2));
    }
    // stage x-tile [64 d][128 s] linear, coalesced float4
    {
        const float* xb = x + ((size_t)b << 17) + s0;    // D*S = 2^17
        #pragma unroll
        for (int i = 0; i < 8; ++i) {
            int f = (i << 8) + tid, d = f >> 5, j = f & 31;
            *(float4*)&xt[d * ST + (j << 2)] =
                *(const float4*)(xb + ((size_t)d << 11) + (j << 2));
        }
    }
    __syncthreads();
    if (tid < ST) {
        float sacc = 0.f;
        #pragma unroll
        for (int d = 0; d < 64; ++d) { float v = xt[d * ST + tid]; sacc = fmaf(v, v, sacc); }
        a2s[tid] = sacc;   // consumed after >=2 barriers below
    }

    float bD[8]; int bK[8];
    #pragma unroll
    for (int j = 0; j < 8; ++j) { bD[j] = 3.4e38f; bK[j] = 0; }

    float* outD = out + O4 + ((size_t)b << 21) + s0;   // K*S = 2^21
    float* outH = out + O2 + ((size_t)b << 21) + s0;

    #pragma unroll 1
    for (int c = 0; c < KE / KC; ++c) {
        const int kc = c << 7;
        lds_barrier();   // prior d-loop reads of u.e done (c=0: covers xt/a2s)
        #pragma unroll
        for (int i = 0; i < 8; ++i) {
            int f = (i << 8) + tid, d = f >> 5, j = f & 31;
            *(float4*)&u.e[d * KC + (j << 2)] = er[i];
        }
        lds_barrier();   // u.e ready
        if (c < KE / KC - 1) {   // issue next chunk's loads; fly under d-loop
            #pragma unroll
            for (int i = 0; i < 8; ++i) {
                int f = (i << 8) + tid, d = f >> 5, j = f & 31;
                er[i] = *(const float4*)(E + (size_t)d * KE + (kc + KC) + (j << 2));
            }
        }

        float acc[8][8];
        #pragma unroll
        for (int jk = 0; jk < 8; ++jk)
            #pragma unroll
            for (int js = 0; js < 8; ++js) acc[jk][js] = 0.f;

        #pragma unroll 2
        for (int d = 0; d < 64; ++d) {
            const float* xp = &xt[d * ST + sq];
            const float* ep = &u.e[d * KC + (ky << 3)];
            float4 xa = *(const float4*)xp;          // s = tx*4..+3   (2-way, 4-lane bcast)
            float4 xb4 = *(const float4*)(xp + 64);  // s = 64+tx*4..+3
            float4 ea = *(const float4*)ep;          // conflict-free, 16-lane bcast
            float4 eb4 = *(const float4*)(ep + 4);
            float xs[8] = {xa.x, xa.y, xa.z, xa.w, xb4.x, xb4.y, xb4.z, xb4.w};
            float es[8] = {ea.x, ea.y, ea.z, ea.w, eb4.x, eb4.y, eb4.z, eb4.w};
            #pragma unroll
            for (int jk = 0; jk < 8; ++jk)
                #pragma unroll
                for (int js = 0; js < 8; ++js)
                    acc[jk][js] = fmaf(es[jk], xs[js], acc[jk][js]);
        }

        // epilogue: dist + argmin + direct stores (full-line 16B quads)
        float4 b2a = *(const float4*)(b2 + kc + (ky << 3));
        float4 b2b = *(const float4*)(b2 + kc + (ky << 3) + 4);
        float b2v[8] = {b2a.x, b2a.y, b2a.z, b2a.w, b2b.x, b2b.y, b2b.z, b2b.w};
        float4 av1 = *(const float4*)&a2s[sq];
        float4 av2 = *(const float4*)&a2s[sq + 64];
        float a2v[8] = {av1.x, av1.y, av1.z, av1.w, av2.x, av2.y, av2.z, av2.w};
        #pragma unroll
        for (int jk = 0; jk < 8; ++jk) {
            const int k = kc + (ky << 3) + jk;
            float dv[8];
            #pragma unroll
            for (int js = 0; js < 8; ++js) {
                dv[js] = fmaf(-2.f, acc[jk][js], a2v[js] + b2v[jk]);
                if (dv[js] < bD[js]) { bD[js] = dv[js]; bK[js] = k; }  // k ascending
            }
            float* pD = outD + ((size_t)k << 11);
            float* pH = outH + ((size_t)k << 11);
            *(F4*)(pD + sq)      = F4{dv[0], dv[1], dv[2], dv[3]};
            *(F4*)(pD + 64 + sq) = F4{dv[4], dv[5], dv[6], dv[7]};
            *(F4*)(pH + sq)      = F4{0.f, 0.f, 0.f, 0.f};
            *(F4*)(pH + 64 + sq) = F4{0.f, 0.f, 0.f, 0.f};
        }
    }

    lds_barrier();   // all d-loop u.e reads done before red overwrite
    #pragma unroll
    for (int js = 0; js < 8; ++js) {
        int sl = sq + (js & 3) + ((js >> 2) << 6);
        u.red.D[ky][sl]  = bD[js];
        u.red.Kk[ky][sl] = bK[js];
    }
    __syncthreads();   // FULL vmcnt drain: every one_hot zero complete before the 1.0 fix

    if (tid < ST) {
        float bDr = u.red.D[0][tid];
        int   bKr = u.red.Kk[0][tid];
        #pragma unroll
        for (int w = 1; w < 16; ++w) {
            float dw = u.red.D[w][tid];
            int   kw = u.red.Kk[w][tid];
            if (dw < bDr || (dw == bDr && kw < bKr)) { bDr = dw; bKr = kw; }  // global first-min
        }
        out[O3 + (size_t)b * SEQ + s0 + tid] = (float)bKr;
        out[O2 + ((size_t)b << 21) + ((size_t)bKr << 11) + s0 + tid] = 1.f;

        // gather codeword, fill qt column (per-thread column: no cross-thread hazard
        // with red region), loss partial
        const float* q = et + ((size_t)bKr << 6);
        float lsum = 0.f;
        #pragma unroll
        for (int i = 0; i < 16; ++i) {
            float4 q4 = ((const float4*)q)[i];
            float qs[4] = {q4.x, q4.y, q4.z, q4.w};
            #pragma unroll
            for (int j = 0; j < 4; ++j) {
                int d = i * 4 + j;
                u.qt[d * ST + tid] = qs[j];
                float df = qs[j] - xt[d * ST + tid];
                lsum = fmaf(df, df, lsum);
            }
        }
        #pragma unroll
        for (int m = 32; m >= 1; m >>= 1) lsum += __shfl_xor(lsum, m, 64);
        if ((tid & 63) == 0) atomicAdd(out + O1, lsum * (2.f / 4194304.f));
    }
    __syncthreads();

    // quantized_st out: [d][s] coalesced float4 (O0 aligned)
    {
        float* oq = out + ((size_t)b << 17) + s0;
        #pragma unroll
        for (int i = 0; i < 8; ++i) {
            int f = (i << 8) + tid, d = f >> 5, sc = (f & 31) << 2;
            *(float4*)(oq + ((size_t)d << 11) + sc) = *(const float4*)&u.qt[d * ST + sc];
        }
    }
    // unquantized out (folded vq_unq): row s0+sl, col lane; 256B/wave-instr stores.
    // LDS read is same-bank serialized (~16 instrs) -- accepted, ~1 us.
    {
        const int lane = tid & 63, sub = tid >> 6;
        float* op = out + O5 + (((size_t)b << 11) + s0) * 64;
        #pragma unroll
        for (int ii = 0; ii < 16; ++ii) {
            int sl = ii * 4 + sub;
            op[(size_t)sl * 64 + lane] = xt[lane * ST + sl];
        }
    }
}

extern "C" void kernel_launch(void* const* d_in, const int* in_sizes, int n_in,
                              void* d_out, int out_size, void* d_ws, size_t ws_size,
                              hipStream_t stream) {
    const float* x = (const float*)d_in[0];
    const float* E = (const float*)d_in[1];
    float* out   = (float*)d_out;
    float* et_ws = (float*)d_ws;          // 65536 floats: E^T rows, 16B-aligned
    float* b2_ws = et_ws + 65536;         // 1024 floats
    vq_prep<<<16, 256, 0, stream>>>(E, out, et_ws, b2_ws);
    vq_main<<<512, 256, 0, stream>>>(x, E, et_ws, b2_ws, out);
}

// Round 8
// 238.750 us; speedup vs baseline: 1.0507x; 1.0361x over previous
//
#include <hip/hip_runtime.h>

#define BSZ 32
#define DIM 64
#define SEQ 2048
#define KE  1024
#define KC  128   // k-chunk staged in LDS
#define ST  128   // s-tile per block

// output offsets in floats
#define O0 0ull            // quantized_st [BS][D][S]
#define O1 4194304ull      // loss (scalar)
#define O2 4194305ull      // one_hot [BS][K][S]
#define O3 71303169ull     // indices [BS][S] (as float)
#define O4 71368705ull     // distance [BS][K][S]
#define O5 138477569ull    // unquantized [BS*S][D]
#define O6 142671873ull    // embeddings.T [K][D]

// 16B store with only 4B alignment guarantee (O2/O4 are odd float offsets).
struct __attribute__((packed, aligned(4))) F4 { float x, y, z, w; };

// lgkm-only barrier: does NOT drain vmcnt -> global stores stay in flight
// across chunk boundaries and drain under the next chunk's compute.
__device__ __forceinline__ void lds_barrier() {
    asm volatile("s_waitcnt lgkmcnt(0)" ::: "memory");
    __builtin_amdgcn_s_barrier();
}

// Kernel 0: transpose E -> out6 + aligned ws copy; b2[k] = ||e_k||^2; zero loss.
__global__ __launch_bounds__(256) void vq_prep(const float* __restrict__ E,
                                               float* __restrict__ out,
                                               float* __restrict__ et_ws,
                                               float* __restrict__ b2_ws) {
    __shared__ float T[64][65];
    const int tid  = threadIdx.x;
    const int lane = tid & 63;
    const int sub  = tid >> 6;
    const int k0   = blockIdx.x * 64;
    for (int dd = 0; dd < 16; ++dd) {
        int d = dd * 4 + sub;
        T[d][lane] = E[(size_t)d * KE + k0 + lane];
    }
    __syncthreads();
    for (int ii = 0; ii < 16; ++ii) {
        int kl = ii * 4 + sub;
        float v = T[lane][kl];
        out[O6 + (size_t)(k0 + kl) * 64 + lane] = v;
        et_ws[(size_t)(k0 + kl) * 64 + lane]    = v;
    }
    if (tid < 64) {
        float s = 0.f;
        #pragma unroll
        for (int d = 0; d < 64; ++d) {
            float v = T[d][tid];
            s = fmaf(v, v, s);
        }
        b2_ws[k0 + tid] = s;
    }
    if (blockIdx.x == 0 && tid == 0) out[O1] = 0.f;
}

// Kernel 1: 512 threads, thread tile 4s x 8k (acc 32 VGPR), launch_bounds(512,4)
// -> 16 waves/CU. Direct full-line F4 stores; lgkm-only barriers; argmin; epilogues.
// grid = 32 b * 16 s-tiles = 512 blocks = 2 blocks/CU.
// Thread: tx = tid&31 (s-quad tx*4..+3), ky = tid>>5 (k-group ky*8..+7).
__global__ __launch_bounds__(512, 4) void vq_main(const float* __restrict__ x,
                                                  const float* __restrict__ E,
                                                  const float* __restrict__ et,
                                                  const float* __restrict__ b2,
                                                  float* __restrict__ out) {
    __shared__ __align__(16) float xt[64 * ST];   // 32 KB x-tile [d][s]
    __shared__ __align__(16) union UU {
        float e[64 * KC];                          // 32 KB e-chunk [d][k]
        struct { float D[16][ST]; int Kk[16][ST]; } red;   // 16 KB
    } u;
    __shared__ __align__(16) float a2s[ST];

    const int tid = threadIdx.x;
    const int tx  = tid & 31;
    const int ky  = tid >> 5;       // 0..15
    const int b   = blockIdx.x >> 4;
    const int s0  = (blockIdx.x & 15) << 7;
    const int sq  = tx << 2;

    // prefetch e-chunk 0 into regs (flies under the x-stage)
    float4 er[4];
    #pragma unroll
    for (int i = 0; i < 4; ++i) {
        int f = (i << 9) + tid, d = f >> 5, j = f & 31;
        er[i] = *(const float4*)(E + (size_t)d * KE + (j << 2));
    }
    // stage x-tile [64 d][128 s], coalesced float4
    {
        const float* xb = x + ((size_t)b << 17) + s0;    // D*S = 2^17
        #pragma unroll
        for (int i = 0; i < 4; ++i) {
            int f = (i << 9) + tid, d = f >> 5, j = f & 31;
            *(float4*)&xt[d * ST + (j << 2)] =
                *(const float4*)(xb + ((size_t)d << 11) + (j << 2));
        }
    }
    __syncthreads();
    if (tid < ST) {
        float sacc = 0.f;
        #pragma unroll
        for (int d = 0; d < 64; ++d) { float v = xt[d * ST + tid]; sacc = fmaf(v, v, sacc); }
        a2s[tid] = sacc;   // visible to all after the next barrier pair
    }

    float bD[4]; int bK[4];
    #pragma unroll
    for (int j = 0; j < 4; ++j) { bD[j] = 3.4e38f; bK[j] = 0; }

    float* outD = out + O4 + ((size_t)b << 21) + s0;   // K*S = 2^21
    float* outH = out + O2 + ((size_t)b << 21) + s0;

    #pragma unroll 1
    for (int c = 0; c < KE / KC; ++c) {
        const int kc = c << 7;
        lds_barrier();   // prior d-loop reads of u.e done (c=0: covers xt/a2s)
        #pragma unroll
        for (int i = 0; i < 4; ++i) {
            int f = (i << 9) + tid, d = f >> 5, j = f & 31;
            *(float4*)&u.e[d * KC + (j << 2)] = er[i];
        }
        lds_barrier();   // u.e ready
        if (c < KE / KC - 1) {   // issue next chunk's loads; fly under d-loop
            #pragma unroll
            for (int i = 0; i < 4; ++i) {
                int f = (i << 9) + tid, d = f >> 5, j = f & 31;
                er[i] = *(const float4*)(E + (size_t)d * KE + (kc + KC) + (j << 2));
            }
        }

        float acc[8][4];
        #pragma unroll
        for (int jk = 0; jk < 8; ++jk)
            #pragma unroll
            for (int js = 0; js < 4; ++js) acc[jk][js] = 0.f;

        #pragma unroll 2
        for (int d = 0; d < 64; ++d) {
            float4 xa = *(const float4*)&xt[d * ST + sq];              // 4 consecutive s
            float4 ea = *(const float4*)&u.e[d * KC + (ky << 3)];     // 8 k, 32-lane bcast
            float4 eb = *(const float4*)&u.e[d * KC + (ky << 3) + 4];
            float xs[4] = {xa.x, xa.y, xa.z, xa.w};
            float es[8] = {ea.x, ea.y, ea.z, ea.w, eb.x, eb.y, eb.z, eb.w};
            #pragma unroll
            for (int jk = 0; jk < 8; ++jk)
                #pragma unroll
                for (int js = 0; js < 4; ++js)
                    acc[jk][js] = fmaf(es[jk], xs[js], acc[jk][js]);
        }

        // epilogue: dist + argmin + direct stores (full-line 16B quads,
        // per wave-instr: 2 k-rows x 512B contiguous)
        float4 b2a = *(const float4*)(b2 + kc + (ky << 3));
        float4 b2b = *(const float4*)(b2 + kc + (ky << 3) + 4);
        float b2v[8] = {b2a.x, b2a.y, b2a.z, b2a.w, b2b.x, b2b.y, b2b.z, b2b.w};
        float4 av = *(const float4*)&a2s[sq];
        float a2v[4] = {av.x, av.y, av.z, av.w};
        #pragma unroll
        for (int jk = 0; jk < 8; ++jk) {
            const int k = kc + (ky << 3) + jk;
            float dv[4];
            #pragma unroll
            for (int js = 0; js < 4; ++js) {
                dv[js] = fmaf(-2.f, acc[jk][js], a2v[js] + b2v[jk]);
                if (dv[js] < bD[js]) { bD[js] = dv[js]; bK[js] = k; }  // k ascending
            }
            float* pD = outD + ((size_t)k << 11);
            float* pH = outH + ((size_t)k << 11);
            *(F4*)(pD + sq) = F4{dv[0], dv[1], dv[2], dv[3]};
            *(F4*)(pH + sq) = F4{0.f, 0.f, 0.f, 0.f};
        }
    }

    lds_barrier();   // all d-loop u.e reads done before red overwrite
    #pragma unroll
    for (int js = 0; js < 4; ++js) {
        u.red.D[ky][sq + js]  = bD[js];
        u.red.Kk[ky][sq + js] = bK[js];
    }
    __syncthreads();   // FULL vmcnt drain: every one_hot zero complete before the 1.0 fix

    if (tid < ST) {
        float bDr = u.red.D[0][tid];
        int   bKr = u.red.Kk[0][tid];
        #pragma unroll
        for (int w = 1; w < 16; ++w) {
            float dw = u.red.D[w][tid];
            int   kw = u.red.Kk[w][tid];
            if (dw < bDr || (dw == bDr && kw < bKr)) { bDr = dw; bKr = kw; }  // global first-min
        }
        out[O3 + (size_t)b * SEQ + s0 + tid] = (float)bKr;
        out[O2 + ((size_t)b << 21) + ((size_t)bKr << 11) + s0 + tid] = 1.f;

        // gather codeword; direct quantized_st store (per d: 128 threads
        // write 128 consecutive floats -> coalesced); loss partial.
        const float* q = et + ((size_t)bKr << 6);
        float* outQ = out + ((size_t)b << 17) + s0 + tid;
        float lsum = 0.f;
        #pragma unroll
        for (int i = 0; i < 16; ++i) {
            float4 q4 = ((const float4*)q)[i];
            float qs[4] = {q4.x, q4.y, q4.z, q4.w};
            #pragma unroll
            for (int j = 0; j < 4; ++j) {
                int d = i * 4 + j;
                outQ[(size_t)d << 11] = qs[j];
                float df = qs[j] - xt[d * ST + tid];
                lsum = fmaf(df, df, lsum);
            }
        }
        #pragma unroll
        for (int m = 32; m >= 1; m >>= 1) lsum += __shfl_xor(lsum, m, 64);
        if ((tid & 63) == 0) atomicAdd(out + O1, lsum * (2.f / 4194304.f));
    }

    // unquantized out (no barrier needed: reads only xt, written before 1st barrier)
    {
        const int lane = tid & 63, sub = tid >> 6;   // sub 0..7
        float* op = out + O5 + (((size_t)b << 11) + s0) * 64;
        #pragma unroll
        for (int ii = 0; ii < 16; ++ii) {
            int sl = ii * 8 + sub;
            op[(size_t)sl * 64 + lane] = xt[lane * ST + sl];
        }
    }
}

extern "C" void kernel_launch(void* const* d_in, const int* in_sizes, int n_in,
                              void* d_out, int out_size, void* d_ws, size_t ws_size,
                              hipStream_t stream) {
    const float* x = (const float*)d_in[0];
    const float* E = (const float*)d_in[1];
    float* out   = (float*)d_out;
    float* et_ws = (float*)d_ws;          // 65536 floats: E^T rows, 16B-aligned
    float* b2_ws = et_ws + 65536;         // 1024 floats
    vq_prep<<<16, 256, 0, stream>>>(E, out, et_ws, b2_ws);
    vq_main<<<512, 512, 0, stream>>>(x, E, et_ws, b2_ws, out);
}